// Round 25
// baseline (74.978 us; speedup 1.0000x reference)
//
#include <hip/hip_runtime.h>
#include <hip/hip_bf16.h>

typedef __attribute__((ext_vector_type(4)))  int   i32x4;
typedef __attribute__((ext_vector_type(16))) int   i32x16;

#define DIM_D 256
#define DIM_O 256
#define DIM_K 8
#define BM 128
#define NCHUNK 16                 // 16 chunks of 16 d-values
#define MAGIC 12582912.f          // 1.5 * 2^23 : fma+byte-extract = rint to int8

// ---- pack kernel: one block per output row o (verified r12-r24) ----
// Per-o scale s_o = max|c[o,:,:]|, quantize into 32x32x32 i8 MFMA B-frag order:
// byte addr = ((s*8 + ct)*64 + lane)*16 + j, where for (o,d,k):
//   s = d>>2, ct = o>>5, lane = ((d>>1)&1)*32 + (o&31), j = (d&1)*8 + k
__global__ __launch_bounds__(256) void pack_w_kernel(
    const float* __restrict__ coeffs,
    unsigned int* __restrict__ wp,
    float* __restrict__ scales)
{
    const int o = blockIdx.x;        // 0..255
    const int d = threadIdx.x;       // 0..255
    const float* cp = coeffs + ((size_t)o * DIM_D + d) * DIM_K;
    float4 c0 = *(const float4*)cp;
    float4 c1 = *(const float4*)(cp + 4);

    float m = fmaxf(fmaxf(fmaxf(fabsf(c0.x), fabsf(c0.y)),
                          fmaxf(fabsf(c0.z), fabsf(c0.w))),
                    fmaxf(fmaxf(fabsf(c1.x), fabsf(c1.y)),
                          fmaxf(fabsf(c1.z), fabsf(c1.w))));
    #pragma unroll
    for (int i = 32; i >= 1; i >>= 1)
        m = fmaxf(m, __shfl_xor(m, i));
    __shared__ float wm[4];
    if ((d & 63) == 0) wm[d >> 6] = m;
    __syncthreads();
    const float sc = fmaxf(fmaxf(fmaxf(wm[0], wm[1]), fmaxf(wm[2], wm[3])),
                           1e-30f);
    if (d == 0) scales[o] = sc;

    const float inv = 127.0f / sc;
    unsigned f0 = __float_as_uint(__builtin_fmaf(c0.x, inv, MAGIC));
    unsigned f1 = __float_as_uint(__builtin_fmaf(c0.y, inv, MAGIC));
    unsigned f2 = __float_as_uint(__builtin_fmaf(c0.z, inv, MAGIC));
    unsigned f3 = __float_as_uint(__builtin_fmaf(c0.w, inv, MAGIC));
    unsigned f4 = __float_as_uint(__builtin_fmaf(c1.x, inv, MAGIC));
    unsigned f5 = __float_as_uint(__builtin_fmaf(c1.y, inv, MAGIC));
    unsigned f6 = __float_as_uint(__builtin_fmaf(c1.z, inv, MAGIC));
    unsigned f7 = __float_as_uint(__builtin_fmaf(c1.w, inv, MAGIC));
    unsigned rA = __builtin_amdgcn_perm(f1, f0, 0x00000400u);
    unsigned rB = __builtin_amdgcn_perm(f3, f2, 0x00000400u);
    unsigned rC = __builtin_amdgcn_perm(f5, f4, 0x00000400u);
    unsigned rD = __builtin_amdgcn_perm(f7, f6, 0x00000400u);
    unsigned lo = __builtin_amdgcn_perm(rB, rA, 0x05040100u);
    unsigned hi = __builtin_amdgcn_perm(rD, rC, 0x05040100u);

    const int base = (((d >> 2) * 8 + (o >> 5)) * 64
                      + ((d >> 1) & 1) * 32 + (o & 31)) * 4 + (d & 1) * 2;
    wp[base]     = lo;
    wp[base + 1] = hi;
}

// tanh + Chebyshev -> 8 orders quantized+packed to 2 u32 (verified r11-r24)
__device__ __forceinline__ void cheb_q8(float xs, unsigned int* o2) {
    float e2 = __expf(2.f * xs);
    float r  = __builtin_amdgcn_rcpf(e2 + 1.f);
    float T1 = __builtin_fmaf(-2.f, r, 1.f);
    float tx = T1 + T1;
    float T2 = __builtin_fmaf(tx, T1, -1.f);
    float T3 = __builtin_fmaf(tx, T2, -T1);
    float T4 = __builtin_fmaf(tx, T3, -T2);
    float T5 = __builtin_fmaf(tx, T4, -T3);
    float T6 = __builtin_fmaf(tx, T5, -T4);
    float T7 = __builtin_fmaf(tx, T6, -T5);
    unsigned f1 = __float_as_uint(__builtin_fmaf(T1, 127.f, MAGIC));
    unsigned f2 = __float_as_uint(__builtin_fmaf(T2, 127.f, MAGIC));
    unsigned f3 = __float_as_uint(__builtin_fmaf(T3, 127.f, MAGIC));
    unsigned f4 = __float_as_uint(__builtin_fmaf(T4, 127.f, MAGIC));
    unsigned f5 = __float_as_uint(__builtin_fmaf(T5, 127.f, MAGIC));
    unsigned f6 = __float_as_uint(__builtin_fmaf(T6, 127.f, MAGIC));
    unsigned f7 = __float_as_uint(__builtin_fmaf(T7, 127.f, MAGIC));
    unsigned rA = __builtin_amdgcn_perm(f2, f1, 0x00000400u);
    unsigned rC = __builtin_amdgcn_perm(f5, f4, 0x00000400u);
    unsigned rD = __builtin_amdgcn_perm(f7, f6, 0x00000400u);
    o2[0] = __builtin_amdgcn_perm(f3, rA, 0x0401000Cu) | 127u;
    o2[1] = __builtin_amdgcn_perm(rD, rC, 0x05040100u);
}

// A-fragment for one (row, k-half) of a 32x32x32 i8 MFMA step: two cheb
// evals for the lane's d-pair — identical payload to the old STAGE2.
__device__ __forceinline__ i32x4 chebA(float2 xp) {
    union { unsigned int u[4]; i32x4 v; } tv;
    cheb_q8(xp.x, &tv.u[0]);
    cheb_q8(xp.y, &tv.u[2]);
    return tv.v;
}

// LDS-free, barrier-free, 2x2 wave split: wave (wr,wc) owns rows
// [wr*64,+64) x cols [wc*128,+128). Each lane computes its own A-frag
// (2x cheb redundancy across the two wc waves; half of r6's 4x). B = 4
// frags/step/wave (half of r16's 8) with 2-deep prefetch. Free-running
// waves drift into anti-phase — the overlap the barriered design never got.
__global__ __launch_bounds__(256, 2) void cfkan_kernel(
    const float* __restrict__ x,
    const i32x4* __restrict__ wp8,
    const float* __restrict__ scales,
    const float* __restrict__ bias,
    float* __restrict__ y)
{
    const int t = threadIdx.x;
    const int wid = t >> 6;          // 0..3
    const int wr = wid >> 1;         // row half
    const int wc = wid & 1;          // col half
    const int l = t & 63;
    const int m = l & 31;            // row (A) / col (B,C) within 32-tile
    const int h = l >> 5;            // k-half: d-pair parity
    // XCD-aware bijective swizzle: grid 512 = 8 XCDs x 64 contiguous blocks
    const int bid = (int)blockIdx.x;
    const int cpx = (int)gridDim.x >> 3;
    const int row0 = ((bid & 7) * cpx + (bid >> 3)) * BM;
    // K-phase rotation, co-resident-decorrelated (bit-identical: integer
    // accumulation is exact and order-independent)
    const int ph = (bid + (bid >> 8) * 5) & 15;
    // start-offset for the co-resident partner (helps drift begin)
    if (bid & 256)
        __builtin_amdgcn_s_sleep(55);

    i32x16 acc[2][4];                // [rt][f]: rows rt*32, col-tile wc*4+f
    #pragma unroll
    for (int rt = 0; rt < 2; ++rt)
        #pragma unroll
        for (int f = 0; f < 4; ++f)
            #pragma unroll
            for (int qi = 0; qi < 16; ++qi)
                acc[rt][f][qi] = 0;

    // per-lane x row bases (float2 at d = sg*4 + h*2)
    const float* xl0 = x + (size_t)(row0 + wr * 64 +      m) * DIM_D + h * 2;
    const float* xl1 = x + (size_t)(row0 + wr * 64 + 32 + m) * DIM_D + h * 2;

#define LOADB4(DST, SG) do {                                               \
    DST[0] = wp8[((SG) * 8 + wc * 4 + 0) * 64 + l];                        \
    DST[1] = wp8[((SG) * 8 + wc * 4 + 1) * 64 + l];                        \
    DST[2] = wp8[((SG) * 8 + wc * 4 + 2) * 64 + l];                        \
    DST[3] = wp8[((SG) * 8 + wc * 4 + 3) * 64 + l];                        \
} while (0)
// one K=32 step: A from registers (cheb), B from bank BB; refill NB for SG2
#define STEPF(BB, NB, SG2, X0, X1) do {                                    \
    i32x4 _nb[4];                                                          \
    LOADB4(_nb, SG2);                                                      \
    i32x4 _a0 = chebA(X0);                                                 \
    i32x4 _a1 = chebA(X1);                                                 \
    _Pragma("unroll")                                                      \
    for (int _f = 0; _f < 4; ++_f) {                                       \
        acc[0][_f] = __builtin_amdgcn_mfma_i32_32x32x32_i8(                \
            _a0, BB[_f], acc[0][_f], 0, 0, 0);                             \
        acc[1][_f] = __builtin_amdgcn_mfma_i32_32x32x32_i8(                \
            _a1, BB[_f], acc[1][_f], 0, 0, 0);                             \
    }                                                                      \
    NB[0] = _nb[0]; NB[1] = _nb[1]; NB[2] = _nb[2]; NB[3] = _nb[3];        \
} while (0)

    // ---- prologue: x(chunk ph) + B(first 2 steps) ----
    float2 xc0[4], xc1[4], xn0[4], xn1[4];
    #pragma unroll
    for (int s = 0; s < 4; ++s) {
        xc0[s] = *(const float2*)(xl0 + (ph * 4 + s) * 4);
        xc1[s] = *(const float2*)(xl1 + (ph * 4 + s) * 4);
    }
    i32x4 b0[4], b1[4];
    LOADB4(b0, ph * 4);
    LOADB4(b1, ph * 4 + 1);

    // ---- main loop: 16 chunks x 4 K=32 steps; no LDS, no barriers ----
    #pragma unroll 1
    for (int ci = 0; ci < NCHUNK; ++ci) {
        const int cc  = (ci + ph) & 15;
        const int ncc = (ci + 1 + ph) & 15;
        const int cc4 = cc * 4, nc4 = ncc * 4;
        // prefetch next chunk's x (one chunk ≈ full HBM latency of cover)
        if (ci < NCHUNK - 1) {
            #pragma unroll
            for (int s = 0; s < 4; ++s) {
                xn0[s] = *(const float2*)(xl0 + (nc4 + s) * 4);
                xn1[s] = *(const float2*)(xl1 + (nc4 + s) * 4);
            }
        }

        STEPF(b0, b0, cc4 + 2, xc0[0], xc1[0]);   // step 0, refill sg+2
        STEPF(b1, b1, cc4 + 3, xc0[1], xc1[1]);   // step 1
        STEPF(b0, b0, nc4 + 0, xc0[2], xc1[2]);   // step 2 -> next chunk s0
        STEPF(b1, b1, nc4 + 1, xc0[3], xc1[3]);   // step 3 -> next chunk s1

        if (ci < NCHUNK - 1) {
            #pragma unroll
            for (int s = 0; s < 4; ++s) { xc0[s] = xn0[s]; xc1[s] = xn1[s]; }
        }
    }

    // ---- epilogue: per-column scale, add bias, store f32 ----
    // C/D 32x32: col = lane&31, row = (qi&3) + 8*(qi>>2) + 4*(lane>>5)
    #pragma unroll
    for (int f = 0; f < 4; ++f) {
        const int col = wc * 128 + f * 32 + m;
        const float sf = scales[col] * (1.f / 16129.f);   // s_o / 127^2
        const float bv = bias[col];
        #pragma unroll
        for (int rt = 0; rt < 2; ++rt) {
            #pragma unroll
            for (int qi = 0; qi < 16; ++qi) {
                const int grow = row0 + wr * 64 + rt * 32
                               + (qi & 3) + 8 * (qi >> 2) + 4 * h;
                y[(size_t)grow * DIM_O + col] =
                    __builtin_fmaf((float)acc[rt][f][qi], sf, bv);
            }
        }
    }
#undef LOADB4
#undef STEPF
}

extern "C" void kernel_launch(void* const* d_in, const int* in_sizes, int n_in,
                              void* d_out, int out_size, void* d_ws, size_t ws_size,
                              hipStream_t stream) {
    const float* x      = (const float*)d_in[0];
    const float* coeffs = (const float*)d_in[1];
    const float* bias   = (const float*)d_in[2];
    float* y = (float*)d_out;
    float*        scales = (float*)d_ws;                      // 1 KB
    unsigned int* wp     = (unsigned int*)((char*)d_ws + 1024); // 512 KB

    const int n_tokens = in_sizes[0] / DIM_D;     // 65536

    pack_w_kernel<<<DIM_O, 256, 0, stream>>>(coeffs, wp, scales);
    cfkan_kernel<<<n_tokens / BM, 256, 0, stream>>>(
        x, (const i32x4*)wp, scales, bias, y);
}

// Round 26
// 72.969 us; speedup vs baseline: 1.0275x; 1.0275x over previous
//
#include <hip/hip_runtime.h>
#include <hip/hip_bf16.h>

typedef __attribute__((ext_vector_type(4)))  int   i32x4;
typedef __attribute__((ext_vector_type(16))) int   i32x16;

#define DIM_D 256
#define DIM_O 256
#define DIM_K 8
#define BM 128
#define NCHUNK 16                 // 16 chunks of 16 d-values
#define MAGIC 12582912.f          // 1.5 * 2^23 : fma+byte-extract = rint to int8

// ---- pack kernel: one block per output row o (verified r12-r25) ----
// Per-o scale s_o = max|c[o,:,:]|, quantize into 32x32x32 i8 MFMA B-frag order:
// byte addr = ((s*8 + ct)*64 + lane)*16 + j, where for (o,d,k):
//   s = d>>2, ct = o>>5, lane = ((d>>1)&1)*32 + (o&31), j = (d&1)*8 + k
__global__ __launch_bounds__(256) void pack_w_kernel(
    const float* __restrict__ coeffs,
    unsigned int* __restrict__ wp,
    float* __restrict__ scales)
{
    const int o = blockIdx.x;        // 0..255
    const int d = threadIdx.x;       // 0..255
    const float* cp = coeffs + ((size_t)o * DIM_D + d) * DIM_K;
    float4 c0 = *(const float4*)cp;
    float4 c1 = *(const float4*)(cp + 4);

    float m = fmaxf(fmaxf(fmaxf(fabsf(c0.x), fabsf(c0.y)),
                          fmaxf(fabsf(c0.z), fabsf(c0.w))),
                    fmaxf(fmaxf(fabsf(c1.x), fabsf(c1.y)),
                          fmaxf(fabsf(c1.z), fabsf(c1.w))));
    #pragma unroll
    for (int i = 32; i >= 1; i >>= 1)
        m = fmaxf(m, __shfl_xor(m, i));
    __shared__ float wm[4];
    if ((d & 63) == 0) wm[d >> 6] = m;
    __syncthreads();
    const float sc = fmaxf(fmaxf(fmaxf(wm[0], wm[1]), fmaxf(wm[2], wm[3])),
                           1e-30f);
    if (d == 0) scales[o] = sc;

    const float inv = 127.0f / sc;
    unsigned f0 = __float_as_uint(__builtin_fmaf(c0.x, inv, MAGIC));
    unsigned f1 = __float_as_uint(__builtin_fmaf(c0.y, inv, MAGIC));
    unsigned f2 = __float_as_uint(__builtin_fmaf(c0.z, inv, MAGIC));
    unsigned f3 = __float_as_uint(__builtin_fmaf(c0.w, inv, MAGIC));
    unsigned f4 = __float_as_uint(__builtin_fmaf(c1.x, inv, MAGIC));
    unsigned f5 = __float_as_uint(__builtin_fmaf(c1.y, inv, MAGIC));
    unsigned f6 = __float_as_uint(__builtin_fmaf(c1.z, inv, MAGIC));
    unsigned f7 = __float_as_uint(__builtin_fmaf(c1.w, inv, MAGIC));
    unsigned rA = __builtin_amdgcn_perm(f1, f0, 0x00000400u);
    unsigned rB = __builtin_amdgcn_perm(f3, f2, 0x00000400u);
    unsigned rC = __builtin_amdgcn_perm(f5, f4, 0x00000400u);
    unsigned rD = __builtin_amdgcn_perm(f7, f6, 0x00000400u);
    unsigned lo = __builtin_amdgcn_perm(rB, rA, 0x05040100u);
    unsigned hi = __builtin_amdgcn_perm(rD, rC, 0x05040100u);

    const int base = (((d >> 2) * 8 + (o >> 5)) * 64
                      + ((d >> 1) & 1) * 32 + (o & 31)) * 4 + (d & 1) * 2;
    wp[base]     = lo;
    wp[base + 1] = hi;
}

// tanh + Chebyshev -> 8 orders quantized+packed to 2 u32 (verified r11-r25)
__device__ __forceinline__ void cheb_q8(float xs, unsigned int* o2) {
    float e2 = __expf(2.f * xs);
    float r  = __builtin_amdgcn_rcpf(e2 + 1.f);
    float T1 = __builtin_fmaf(-2.f, r, 1.f);
    float tx = T1 + T1;
    float T2 = __builtin_fmaf(tx, T1, -1.f);
    float T3 = __builtin_fmaf(tx, T2, -T1);
    float T4 = __builtin_fmaf(tx, T3, -T2);
    float T5 = __builtin_fmaf(tx, T4, -T3);
    float T6 = __builtin_fmaf(tx, T5, -T4);
    float T7 = __builtin_fmaf(tx, T6, -T5);
    unsigned f1 = __float_as_uint(__builtin_fmaf(T1, 127.f, MAGIC));
    unsigned f2 = __float_as_uint(__builtin_fmaf(T2, 127.f, MAGIC));
    unsigned f3 = __float_as_uint(__builtin_fmaf(T3, 127.f, MAGIC));
    unsigned f4 = __float_as_uint(__builtin_fmaf(T4, 127.f, MAGIC));
    unsigned f5 = __float_as_uint(__builtin_fmaf(T5, 127.f, MAGIC));
    unsigned f6 = __float_as_uint(__builtin_fmaf(T6, 127.f, MAGIC));
    unsigned f7 = __float_as_uint(__builtin_fmaf(T7, 127.f, MAGIC));
    unsigned rA = __builtin_amdgcn_perm(f2, f1, 0x00000400u);
    unsigned rC = __builtin_amdgcn_perm(f5, f4, 0x00000400u);
    unsigned rD = __builtin_amdgcn_perm(f7, f6, 0x00000400u);
    o2[0] = __builtin_amdgcn_perm(f3, rA, 0x0401000Cu) | 127u;
    o2[1] = __builtin_amdgcn_perm(rD, rC, 0x05040100u);
}

// A-fragment for one 32x32x32 i8 step: lane's own (row, d-pair)
__device__ __forceinline__ i32x4 chebA(float2 xp) {
    union { unsigned int u[4]; i32x4 v; } tv;
    cheb_q8(xp.x, &tv.u[0]);
    cheb_q8(xp.y, &tv.u[2]);
    return tv.v;
}

// Row-split, LDS-free, barrier-free: wave w owns rows [w*32,+32) x ALL 256
// cols. A is lane-local (row = l&31, d-pair = 4s + 2*(l>>5)): exactly ONE
// chebA per lane per step — zero redundancy (r6/r25's flaw), zero LDS
// (16 us pipe term in r24), zero barriers (lockstep broken). B: 8 frags/step
// shared by all 4 waves -> L1-filtered; 1-deep ping-pong banks, no copies
// (r16's spill came from the copy-temp structure).
__global__ __launch_bounds__(256, 2) void cfkan_kernel(
    const float* __restrict__ x,
    const i32x4* __restrict__ wp8,
    const float* __restrict__ scales,
    const float* __restrict__ bias,
    float* __restrict__ y)
{
    const int t = threadIdx.x;
    const int w = t >> 6;            // wave 0..3 -> rows [32w, 32w+32)
    const int l = t & 63;
    const int m = l & 31;            // row (A) / col (B,C) within 32-tile
    const int h = l >> 5;            // k-half -> d-pair parity
    // XCD-aware bijective swizzle: grid 512 = 8 XCDs x 64 contiguous blocks
    const int bid = (int)blockIdx.x;
    const int cpx = (int)gridDim.x >> 3;
    const int row0 = ((bid & 7) * cpx + (bid >> 3)) * BM;
    // K-phase rotation, co-resident-decorrelated (bit-identical: integer
    // accumulation is exact and order-independent)
    const int ph = (bid + (bid >> 8) * 5) & 15;

    i32x16 acc[8];
    #pragma unroll
    for (int f = 0; f < 8; ++f)
        #pragma unroll
        for (int qi = 0; qi < 16; ++qi)
            acc[f][qi] = 0;

    // lane's x base: its own row, its d-pair parity; step sg -> +sg*4
    const float* xl = x + (size_t)(row0 + w * 32 + m) * DIM_D + h * 2;
    const i32x4* wl = wp8 + l;

#define LOADB8(DST, SG) do {                                               \
    DST[0] = wl[((SG) * 8 + 0) * 64];                                      \
    DST[1] = wl[((SG) * 8 + 1) * 64];                                      \
    DST[2] = wl[((SG) * 8 + 2) * 64];                                      \
    DST[3] = wl[((SG) * 8 + 3) * 64];                                      \
    DST[4] = wl[((SG) * 8 + 4) * 64];                                      \
    DST[5] = wl[((SG) * 8 + 5) * 64];                                      \
    DST[6] = wl[((SG) * 8 + 6) * 64];                                      \
    DST[7] = wl[((SG) * 8 + 7) * 64];                                      \
} while (0)
// one K=32 step: issue next step's B into FILL (free bank), compute this
// lane's A-frag (~42 VALU covers the L1/L2 latency), 8 MFMAs from USE.
#define STEPR(USE, FILL, SGN, XP) do {                                     \
    LOADB8(FILL, SGN);                                                     \
    i32x4 _a = chebA(XP);                                                  \
    _Pragma("unroll")                                                      \
    for (int _f = 0; _f < 8; ++_f)                                         \
        acc[_f] = __builtin_amdgcn_mfma_i32_32x32x32_i8(                   \
            _a, USE[_f], acc[_f], 0, 0, 0);                                \
} while (0)

    // ---- prologue: x(chunk ph) + B(step ph*4) ----
    float2 xq[4], xn[4];
    #pragma unroll
    for (int s = 0; s < 4; ++s)
        xq[s] = *(const float2*)(xl + (ph * 4 + s) * 4);
    i32x4 b0[8], b1[8];
    LOADB8(b0, ph * 4);

    // ---- main loop: 16 chunks x 4 K=32 steps; no LDS, no barriers ----
    #pragma unroll 1
    for (int ci = 0; ci < NCHUNK; ++ci) {
        const int cc  = (ci + ph) & 15;
        const int ncc = (ci + 1 + ph) & 15;
        const int cc4 = cc * 4, nc4 = ncc * 4;
        // prefetch next chunk's x (consumed ~a full chunk later)
        if (ci < NCHUNK - 1) {
            #pragma unroll
            for (int s = 0; s < 4; ++s)
                xn[s] = *(const float2*)(xl + (nc4 + s) * 4);
        }

        STEPR(b0, b1, cc4 + 1, xq[0]);   // s0: use b0, fill b1 for s1
        STEPR(b1, b0, cc4 + 2, xq[1]);   // s1
        STEPR(b0, b1, cc4 + 3, xq[2]);   // s2
        STEPR(b1, b0, nc4 + 0, xq[3]);   // s3: fill next chunk's s0

        if (ci < NCHUNK - 1) {
            #pragma unroll
            for (int s = 0; s < 4; ++s) xq[s] = xn[s];
        }
    }

    // ---- epilogue: per-column scale, add bias, store f32 ----
    // C/D 32x32: col = lane&31, row = (qi&3) + 8*(qi>>2) + 4*(lane>>5)
    #pragma unroll
    for (int f = 0; f < 8; ++f) {
        const int col = f * 32 + m;
        const float sf = scales[col] * (1.f / 16129.f);   // s_o / 127^2
        const float bv = bias[col];
        #pragma unroll
        for (int qi = 0; qi < 16; ++qi) {
            const int grow = row0 + w * 32 + (qi & 3) + 8 * (qi >> 2) + 4 * h;
            y[(size_t)grow * DIM_O + col] =
                __builtin_fmaf((float)acc[f][qi], sf, bv);
        }
    }
#undef LOADB8
#undef STEPR
}

extern "C" void kernel_launch(void* const* d_in, const int* in_sizes, int n_in,
                              void* d_out, int out_size, void* d_ws, size_t ws_size,
                              hipStream_t stream) {
    const float* x      = (const float*)d_in[0];
    const float* coeffs = (const float*)d_in[1];
    const float* bias   = (const float*)d_in[2];
    float* y = (float*)d_out;
    float*        scales = (float*)d_ws;                      // 1 KB
    unsigned int* wp     = (unsigned int*)((char*)d_ws + 1024); // 512 KB

    const int n_tokens = in_sizes[0] / DIM_D;     // 65536

    pack_w_kernel<<<DIM_O, 256, 0, stream>>>(coeffs, wp, scales);
    cfkan_kernel<<<n_tokens / BM, 256, 0, stream>>>(
        x, (const i32x4*)wp, scales, bias, y);
}

// Round 27
// 53.122 us; speedup vs baseline: 1.4114x; 1.3736x over previous
//
#include <hip/hip_runtime.h>
#include <hip/hip_bf16.h>

typedef __attribute__((ext_vector_type(4)))  int   i32x4;
typedef __attribute__((ext_vector_type(16))) int   i32x16;

#define DIM_D 256
#define DIM_O 256
#define DIM_K 8
#define BM 128
#define NCHUNK 16                 // 16 chunks of 16 d-values
#define NSTEP 4                   // 4 K=32 steps per chunk (4 d's each)
#define MAGIC 12582912.f          // 1.5 * 2^23 : fma+byte-extract = rint to int8

// ---- pack kernel: one block per output row o (verified r12-r24) ----
// Per-o scale s_o = max|c[o,:,:]|, quantize into 32x32x32 i8 MFMA B-frag order:
// byte addr = ((s*8 + ct)*64 + lane)*16 + j, where for (o,d,k):
//   s = d>>2, ct = o>>5, lane = ((d>>1)&1)*32 + (o&31), j = (d&1)*8 + k
__global__ __launch_bounds__(256) void pack_w_kernel(
    const float* __restrict__ coeffs,
    unsigned int* __restrict__ wp,
    float* __restrict__ scales)
{
    const int o = blockIdx.x;        // 0..255
    const int d = threadIdx.x;       // 0..255
    const float* cp = coeffs + ((size_t)o * DIM_D + d) * DIM_K;
    float4 c0 = *(const float4*)cp;
    float4 c1 = *(const float4*)(cp + 4);

    float m = fmaxf(fmaxf(fmaxf(fabsf(c0.x), fabsf(c0.y)),
                          fmaxf(fabsf(c0.z), fabsf(c0.w))),
                    fmaxf(fmaxf(fabsf(c1.x), fabsf(c1.y)),
                          fmaxf(fabsf(c1.z), fabsf(c1.w))));
    #pragma unroll
    for (int i = 32; i >= 1; i >>= 1)
        m = fmaxf(m, __shfl_xor(m, i));
    __shared__ float wm[4];
    if ((d & 63) == 0) wm[d >> 6] = m;
    __syncthreads();
    const float sc = fmaxf(fmaxf(fmaxf(wm[0], wm[1]), fmaxf(wm[2], wm[3])),
                           1e-30f);
    if (d == 0) scales[o] = sc;

    const float inv = 127.0f / sc;
    unsigned f0 = __float_as_uint(__builtin_fmaf(c0.x, inv, MAGIC));
    unsigned f1 = __float_as_uint(__builtin_fmaf(c0.y, inv, MAGIC));
    unsigned f2 = __float_as_uint(__builtin_fmaf(c0.z, inv, MAGIC));
    unsigned f3 = __float_as_uint(__builtin_fmaf(c0.w, inv, MAGIC));
    unsigned f4 = __float_as_uint(__builtin_fmaf(c1.x, inv, MAGIC));
    unsigned f5 = __float_as_uint(__builtin_fmaf(c1.y, inv, MAGIC));
    unsigned f6 = __float_as_uint(__builtin_fmaf(c1.z, inv, MAGIC));
    unsigned f7 = __float_as_uint(__builtin_fmaf(c1.w, inv, MAGIC));
    unsigned rA = __builtin_amdgcn_perm(f1, f0, 0x00000400u);
    unsigned rB = __builtin_amdgcn_perm(f3, f2, 0x00000400u);
    unsigned rC = __builtin_amdgcn_perm(f5, f4, 0x00000400u);
    unsigned rD = __builtin_amdgcn_perm(f7, f6, 0x00000400u);
    unsigned lo = __builtin_amdgcn_perm(rB, rA, 0x05040100u);
    unsigned hi = __builtin_amdgcn_perm(rD, rC, 0x05040100u);

    const int base = (((d >> 2) * 8 + (o >> 5)) * 64
                      + ((d >> 1) & 1) * 32 + (o & 31)) * 4 + (d & 1) * 2;
    wp[base]     = lo;
    wp[base + 1] = hi;
}

// tanh + Chebyshev -> 8 orders quantized+packed to 2 u32 (verified r11-r24)
__device__ __forceinline__ void cheb_q8(float xs, unsigned int* o2) {
    float e2 = __expf(2.f * xs);
    float r  = __builtin_amdgcn_rcpf(e2 + 1.f);
    float T1 = __builtin_fmaf(-2.f, r, 1.f);
    float tx = T1 + T1;
    float T2 = __builtin_fmaf(tx, T1, -1.f);
    float T3 = __builtin_fmaf(tx, T2, -T1);
    float T4 = __builtin_fmaf(tx, T3, -T2);
    float T5 = __builtin_fmaf(tx, T4, -T3);
    float T6 = __builtin_fmaf(tx, T5, -T4);
    float T7 = __builtin_fmaf(tx, T6, -T5);
    unsigned f1 = __float_as_uint(__builtin_fmaf(T1, 127.f, MAGIC));
    unsigned f2 = __float_as_uint(__builtin_fmaf(T2, 127.f, MAGIC));
    unsigned f3 = __float_as_uint(__builtin_fmaf(T3, 127.f, MAGIC));
    unsigned f4 = __float_as_uint(__builtin_fmaf(T4, 127.f, MAGIC));
    unsigned f5 = __float_as_uint(__builtin_fmaf(T5, 127.f, MAGIC));
    unsigned f6 = __float_as_uint(__builtin_fmaf(T6, 127.f, MAGIC));
    unsigned f7 = __float_as_uint(__builtin_fmaf(T7, 127.f, MAGIC));
    unsigned rA = __builtin_amdgcn_perm(f2, f1, 0x00000400u);
    unsigned rC = __builtin_amdgcn_perm(f5, f4, 0x00000400u);
    unsigned rD = __builtin_amdgcn_perm(f7, f6, 0x00000400u);
    o2[0] = __builtin_amdgcn_perm(f3, rA, 0x0401000Cu) | 127u;
    o2[1] = __builtin_amdgcn_perm(rD, rC, 0x05040100u);
}

__global__ __launch_bounds__(256, 2) void cfkan_kernel(
    const float* __restrict__ x,
    const i32x4* __restrict__ wp8,
    const float* __restrict__ scales,
    const float* __restrict__ bias,
    float* __restrict__ y)
{
    // double-buffered i8 A tile: [row][8 slots of 16B], slot XOR-swizzle; 32 KB
    __shared__ unsigned char Abuf[2][BM][128];

    const int t = threadIdx.x;
    const int w = t >> 6;            // wave 0..3 -> output cols [64w, 64w+64)
    const int l = t & 63;
    const int m = l & 31;            // A row / B,C col within 32-tile
    const int h = l >> 5;            // k-half: d-pair parity
    // XCD-aware bijective swizzle: grid 512 = 8 XCDs x 64 contiguous blocks
    const int bid = (int)blockIdx.x;
    const int cpx = (int)gridDim.x >> 3;
    const int row0 = ((bid & 7) * cpx + (bid >> 3)) * BM;
    // K-phase rotation, co-resident-decorrelated: pairs (bid, bid+256) share
    // a SIMD; ensure they get DIFFERENT phases (bit-identical output:
    // integer accumulation is exact and order-independent)
    const int ph = (bid + (bid >> 8) * 5) & 15;

    // Temporal de-phasing: delay the second co-resident (bid>=256) by
    // ~half a chunk period (~3500 cyc) so its VALU/stage phase overlaps
    // the partner's MFMA phase instead of lockstepping with it.
    if (bid & 256)
        __builtin_amdgcn_s_sleep(55);   // ~55*64 ≈ 3520 cyc

    i32x16 acc[4][2];
    #pragma unroll
    for (int rt = 0; rt < 4; ++rt)
        #pragma unroll
        for (int ct = 0; ct < 2; ++ct)
            #pragma unroll
            for (int qi = 0; qi < 16; ++qi)
                acc[rt][ct][qi] = 0;

    const int lrow = t >> 1;         // 0..127 (row this thread stages)
    const int half = t & 1;          // which 8 of the 16 chunk-d's
    const float* xrow = x + (size_t)(row0 + lrow) * DIM_D + half * 8;

// A-frag read: step S, lane -> rows rt*32+m, slot (2S+h), XOR by row&7
#define READA(DST, AB, S) do {                                             \
    const int _so = (((2 * (S) + h) ^ (m & 7)) * 16);                      \
    DST[0] = *(const i32x4*)&AB[      m][_so];                             \
    DST[1] = *(const i32x4*)&AB[ 32 + m][_so];                             \
    DST[2] = *(const i32x4*)&AB[ 64 + m][_so];                             \
    DST[3] = *(const i32x4*)&AB[ 96 + m][_so];                             \
} while (0)
#define LOADB2(DST, SG) do {                                               \
    DST[0] = wp8[((SG) * 8 + w * 2 + 0) * 64 + l];                         \
    DST[1] = wp8[((SG) * 8 + w * 2 + 1) * 64 + l];                         \
} while (0)
// stage d-pair {2S, 2S+1} of the staged chunk: one swizzled ds_write_b128
#define STAGE2(ANX, S, X0, X1) do {                                        \
    union { unsigned int u[4]; i32x4 v; } _tv;                             \
    cheb_q8(X0, &_tv.u[0]);                                                \
    cheb_q8(X1, &_tv.u[2]);                                                \
    *(i32x4*)&ANX[lrow][(((half * 4 + (S)) ^ (lrow & 7)) * 16)] = _tv.v;   \
} while (0)
// barrier draining ONLY LDS ops; global loads stay in flight (T4)
#define SOFT_BARRIER() do {                                                \
    asm volatile("s_waitcnt lgkmcnt(0)" ::: "memory");                     \
    __builtin_amdgcn_s_barrier();                                          \
    __builtin_amdgcn_sched_barrier(0);                                     \
} while (0)

    // ---- prologue: stage chunk ph; preload x(ph+1) + B(first 2 steps) ----
    float xv[8];
    {
        float4 a0 = *(const float4*)(xrow + ph * 16);
        float4 a1 = *(const float4*)(xrow + ph * 16 + 4);
        float xs[8] = {a0.x, a0.y, a0.z, a0.w, a1.x, a1.y, a1.z, a1.w};
        #pragma unroll
        for (int s = 0; s < 4; ++s)
            STAGE2(Abuf[0], s, xs[2 * s], xs[2 * s + 1]);
        const int c1 = (ph + 1) & 15;
        float4 b0 = *(const float4*)(xrow + c1 * 16);
        float4 b1 = *(const float4*)(xrow + c1 * 16 + 4);
        xv[0] = b0.x; xv[1] = b0.y; xv[2] = b0.z; xv[3] = b0.w;
        xv[4] = b1.x; xv[5] = b1.y; xv[6] = b1.z; xv[7] = b1.w;
    }
    i32x4 bq[NSTEP + 2][2];          // 2-deep B pipeline (static idx via unroll)
    LOADB2(bq[0], ph * 4);
    LOADB2(bq[1], ph * 4 + 1);
    SOFT_BARRIER();
    i32x4 r[4], rn[4];
    READA(r, Abuf[0], 0);

    // ---- main loop: 4 K=32 steps/chunk, fine interleave, soft barrier ----
    #pragma unroll 1
    for (int ci = 0; ci < NCHUNK; ++ci) {
        const int cc  = (ci + ph) & 15;       // chunk processed this iter
        const int ncc = (ci + 1 + ph) & 15;   // chunk staged this iter
        const unsigned char (*A)[128] = Abuf[ci & 1];
        unsigned char (*ANX)[128]     = Abuf[(ci & 1) ^ 1];
        const bool stage = (ci < NCHUNK - 1);
        float4 xn0, xn1;
        if (ci + 2 < NCHUNK) {
            const int c2 = (ci + 2 + ph) & 15;
            xn0 = *(const float4*)(xrow + c2 * 16);
            xn1 = *(const float4*)(xrow + c2 * 16 + 4);
        }
        const int cc4 = cc * 4, nc4 = ncc * 4;

        #pragma unroll
        for (int s = 0; s < NSTEP; ++s) {
            // 2-steps-ahead B prefetch, following the rotated sequence
            const int tgt = (s < 2) ? (cc4 + s + 2) : (nc4 + s - 2);
            LOADB2(bq[s + 2], tgt);
            if (s < NSTEP - 1) READA(rn, A, s + 1);

            __builtin_amdgcn_s_setprio(1);
            #pragma unroll
            for (int rt = 0; rt < 4; ++rt) {
                acc[rt][0] = __builtin_amdgcn_mfma_i32_32x32x32_i8(
                    r[rt], bq[s][0], acc[rt][0], 0, 0, 0);
                acc[rt][1] = __builtin_amdgcn_mfma_i32_32x32x32_i8(
                    r[rt], bq[s][1], acc[rt][1], 0, 0, 0);
            }
            __builtin_amdgcn_s_setprio(0);

            if (stage) STAGE2(ANX, s, xv[2 * s], xv[2 * s + 1]);

            if (s < NSTEP - 1) { r[0] = rn[0]; r[1] = rn[1]; r[2] = rn[2]; r[3] = rn[3]; }
        }
        bq[0][0] = bq[4][0]; bq[0][1] = bq[4][1];     // carry the pipeline
        bq[1][0] = bq[5][0]; bq[1][1] = bq[5][1];
        if (ci + 2 < NCHUNK) {
            xv[0] = xn0.x; xv[1] = xn0.y; xv[2] = xn0.z; xv[3] = xn0.w;
            xv[4] = xn1.x; xv[5] = xn1.y; xv[6] = xn1.z; xv[7] = xn1.w;
        }
        SOFT_BARRIER();
        if (ci < NCHUNK - 1) READA(r, ANX, 0);        // next chunk's step-0 frags
    }

    // ---- epilogue: per-column scale, add bias, store f32 ----
    // C/D 32x32: col = lane&31, row = (qi&3) + 8*(qi>>2) + 4*(lane>>5)
    #pragma unroll
    for (int ct = 0; ct < 2; ++ct) {
        const int col = w * 64 + ct * 32 + m;
        const float sf = scales[col] * (1.f / 16129.f);   // s_o / 127^2
        const float bv = bias[col];
        #pragma unroll
        for (int rt = 0; rt < 4; ++rt) {
            #pragma unroll
            for (int qi = 0; qi < 16; ++qi) {
                const int grow = row0 + rt * 32 + (qi & 3) + 8 * (qi >> 2) + 4 * h;
                y[(size_t)grow * DIM_O + col] =
                    __builtin_fmaf((float)acc[rt][ct][qi], sf, bv);
            }
        }
    }
#undef READA
#undef LOADB2
#undef STAGE2
#undef SOFT_BARRIER
}

extern "C" void kernel_launch(void* const* d_in, const int* in_sizes, int n_in,
                              void* d_out, int out_size, void* d_ws, size_t ws_size,
                              hipStream_t stream) {
    const float* x      = (const float*)d_in[0];
    const float* coeffs = (const float*)d_in[1];
    const float* bias   = (const float*)d_in[2];
    float* y = (float*)d_out;
    float*        scales = (float*)d_ws;                      // 1 KB
    unsigned int* wp     = (unsigned int*)((char*)d_ws + 1024); // 512 KB

    const int n_tokens = in_sizes[0] / DIM_D;     // 65536

    pack_w_kernel<<<DIM_O, 256, 0, stream>>>(coeffs, wp, scales);
    cfkan_kernel<<<n_tokens / BM, 256, 0, stream>>>(
        x, (const i32x4*)wp, scales, bias, y);
}